// Round 1
// baseline (129.871 us; speedup 1.0000x reference)
//
#include <hip/hip_runtime.h>
#include <hip/hip_bf16.h>

#define N_PAIR 8192
#define DIM 128
#define L2REG 0.05f
#define LOG2E 1.44269504088896340736f
#define LN2 0.69314718055994530942f

#define BR 64           // rows per block (4 waves x 16 rows)
#define CS 4            // column splits
#define COLS_PER (N_PAIR / CS)   // 2048

typedef __attribute__((ext_vector_type(8))) short short8;
typedef __attribute__((ext_vector_type(4))) float f32x4;

// ---------------- prep: deinterleave, cast to bf16, norms + diag ----------------
// one wave per pair i: anc = row 2i, pos = row 2i+1
__global__ __launch_bounds__(64) void prep_kernel(
    const float* __restrict__ img,
    ushort* __restrict__ anc_bf, ushort* __restrict__ pos_bf,
    float* __restrict__ diag, float* __restrict__ na, float* __restrict__ npn) {
  int i = blockIdx.x;
  int lane = threadIdx.x;  // 0..63, handles 2 elements
  const float2* ar = (const float2*)(img + (size_t)(2 * i) * DIM);
  const float2* pr = (const float2*)(img + (size_t)(2 * i + 1) * DIM);
  float2 a2 = ar[lane];
  float2 p2 = pr[lane];

  __hip_bfloat16 ax = __float2bfloat16(a2.x), ay = __float2bfloat16(a2.y);
  __hip_bfloat16 px = __float2bfloat16(p2.x), py = __float2bfloat16(p2.y);
  ushort2 av, pv;
  av.x = *(ushort*)&ax; av.y = *(ushort*)&ay;
  pv.x = *(ushort*)&px; pv.y = *(ushort*)&py;
  *(ushort2*)(anc_bf + (size_t)i * DIM + 2 * lane) = av;
  *(ushort2*)(pos_bf + (size_t)i * DIM + 2 * lane) = pv;

  float sa = a2.x * a2.x + a2.y * a2.y;
  float sp = p2.x * p2.x + p2.y * p2.y;
  float sd = a2.x * p2.x + a2.y * p2.y;
  #pragma unroll
  for (int off = 32; off; off >>= 1) {
    sa += __shfl_xor(sa, off);
    sp += __shfl_xor(sp, off);
    sd += __shfl_xor(sd, off);
  }
  if (lane == 0) {
    diag[i] = sd;
    na[i] = sqrtf(sa);
    npn[i] = sqrtf(sp);
  }
}

// ---------------- main: fused GEMM (bf16 MFMA) + online LSE ----------------
// grid = (N_PAIR/BR) * CS blocks, 256 threads (4 waves, 16 rows each).
// Each block: rows [rb*BR, rb*BR+64), cols [cs*2048, cs*2048+2048).
// Writes split-LSE partials (m, s) per (row, cs).
__global__ __launch_bounds__(256) void lse_kernel(
    const ushort* __restrict__ anc_bf, const ushort* __restrict__ pos_bf,
    float* __restrict__ part_m, float* __restrict__ part_s) {
  int tid = threadIdx.x;
  int w = tid >> 6;        // wave 0..3
  int lane = tid & 63;
  int rb = blockIdx.x / CS;
  int cs = blockIdx.x % CS;
  int row0 = rb * BR + w * 16;
  int colbase = cs * COLS_PER;
  int lrow = lane & 15;    // A row / B col within tile
  int g = lane >> 4;       // k-group

  // A fragments: 16 rows x 128 K, resident in registers
  short8 afrag[4];
  const ushort* abase = anc_bf + (size_t)(row0 + lrow) * DIM + g * 8;
  #pragma unroll
  for (int ks = 0; ks < 4; ++ks)
    afrag[ks] = *(const short8*)(abase + ks * 32);

  float m[4] = {-1e30f, -1e30f, -1e30f, -1e30f};
  float s[4] = {0.f, 0.f, 0.f, 0.f};

  const ushort* bcol = pos_bf + (size_t)(colbase + lrow) * DIM + g * 8;
  for (int ct = 0; ct < COLS_PER / 16; ++ct) {
    const ushort* bp = bcol + (size_t)ct * 16 * DIM;
    short8 bfrag[4];
    #pragma unroll
    for (int ks = 0; ks < 4; ++ks)
      bfrag[ks] = *(const short8*)(bp + ks * 32);
    f32x4 acc = {0.f, 0.f, 0.f, 0.f};
    #pragma unroll
    for (int ks = 0; ks < 4; ++ks)
      acc = __builtin_amdgcn_mfma_f32_16x16x32_bf16(afrag[ks], bfrag[ks], acc, 0, 0, 0);
    // online LSE update: lane's acc[r] is G[row0 + g*4 + r][col tile, col lane lrow]
    #pragma unroll
    for (int r = 0; r < 4; ++r) {
      float y = acc[r] * LOG2E;
      float mn = fmaxf(m[r], y);
      s[r] = s[r] * exp2f(m[r] - mn) + exp2f(y - mn);
      m[r] = mn;
    }
  }

  // merge (m,s) across the 16 lanes sharing each row
  #pragma unroll
  for (int r = 0; r < 4; ++r) {
    float mm = m[r], ss = s[r];
    #pragma unroll
    for (int off = 1; off < 16; off <<= 1) {
      float m2 = __shfl_xor(mm, off);
      float s2 = __shfl_xor(ss, off);
      float mn = fmaxf(mm, m2);
      ss = ss * exp2f(mm - mn) + s2 * exp2f(m2 - mn);
      mm = mn;
    }
    if (lrow == 0) {
      int grow = row0 + g * 4 + r;
      part_m[(size_t)grow * CS + cs] = mm;
      part_s[(size_t)grow * CS + cs] = ss;
    }
  }
}

// ---------------- merge: combine column splits, add diag/norm terms ----------------
__global__ __launch_bounds__(256) void merge_kernel(
    const float* __restrict__ part_m, const float* __restrict__ part_s,
    const float* __restrict__ diag, const float* __restrict__ na,
    const float* __restrict__ npn, float* __restrict__ blocksum) {
  int i = blockIdx.x * 256 + threadIdx.x;
  float pm[CS], ps[CS];
  float M = -1e30f;
  #pragma unroll
  for (int c = 0; c < CS; ++c) {
    pm[c] = part_m[(size_t)i * CS + c];
    ps[c] = part_s[(size_t)i * CS + c];
    M = fmaxf(M, pm[c]);
  }
  float S = 0.f;
  #pragma unroll
  for (int c = 0; c < CS; ++c) S += ps[c] * exp2f(pm[c] - M);
  float lse = (M + log2f(S)) * LN2;
  float contrib = (lse - diag[i]) * (1.0f / N_PAIR)
                + L2REG * (na[i] * (1.0f / N_PAIR) + npn[i] * (1.0f / DIM));
  // block reduce (2 stages: wave shuffle then LDS)
  #pragma unroll
  for (int off = 32; off; off >>= 1) contrib += __shfl_xor(contrib, off);
  __shared__ float red[4];
  int lane = threadIdx.x & 63, wv = threadIdx.x >> 6;
  if (lane == 0) red[wv] = contrib;
  __syncthreads();
  if (threadIdx.x == 0)
    blocksum[blockIdx.x] = red[0] + red[1] + red[2] + red[3];
}

// ---------------- final: reduce 32 block sums ----------------
__global__ __launch_bounds__(64) void final_kernel(
    const float* __restrict__ blocksum, float* __restrict__ out, int nblocks) {
  float v = ((int)threadIdx.x < nblocks) ? blocksum[threadIdx.x] : 0.f;
  #pragma unroll
  for (int off = 32; off; off >>= 1) v += __shfl_xor(v, off);
  if (threadIdx.x == 0) out[0] = v;
}

extern "C" void kernel_launch(void* const* d_in, const int* in_sizes, int n_in,
                              void* d_out, int out_size, void* d_ws, size_t ws_size,
                              hipStream_t stream) {
  const float* img = (const float*)d_in[0];
  float* out = (float*)d_out;

  char* w = (char*)d_ws;
  ushort* anc_bf = (ushort*)w;                                  // 2 MB
  ushort* pos_bf = (ushort*)(w + (size_t)2 * 1024 * 1024);      // 2 MB
  float* diag = (float*)(w + (size_t)4 * 1024 * 1024);          // 32 KB
  float* na = diag + N_PAIR;                                    // 32 KB
  float* npn = na + N_PAIR;                                     // 32 KB
  float* part_m = npn + N_PAIR;                                 // 128 KB
  float* part_s = part_m + (size_t)N_PAIR * CS;                 // 128 KB
  float* blocksum = part_s + (size_t)N_PAIR * CS;               // 128 B

  prep_kernel<<<N_PAIR, 64, 0, stream>>>(img, anc_bf, pos_bf, diag, na, npn);
  lse_kernel<<<(N_PAIR / BR) * CS, 256, 0, stream>>>(anc_bf, pos_bf, part_m, part_s);
  merge_kernel<<<N_PAIR / 256, 256, 0, stream>>>(part_m, part_s, diag, na, npn, blocksum);
  final_kernel<<<1, 64, 0, stream>>>(blocksum, out, N_PAIR / 256);
}

// Round 2
// 55.120 us; speedup vs baseline: 2.3562x; 2.3562x over previous
//
#include <hip/hip_runtime.h>
#include <hip/hip_bf16.h>
#include <math.h>

#define N_PAIR 8192
#define DIM 128
#define L2REG 0.05f
#define LOG2E 1.44269504088896340736f
#define LN2 0.69314718055994530942f
#define SHIFT 64.0f

#define CS 32                          // column splits
#define ROWS_PER_BLOCK 256             // 4 waves x 64 rows
#define COLS_PER_BLOCK (N_PAIR / CS)   // 256
#define CT_PER_BLOCK (COLS_PER_BLOCK / 16)  // 16 col tiles

typedef __attribute__((ext_vector_type(8))) short short8;
typedef __attribute__((ext_vector_type(4))) float f32x4;

// ---------------- prep: deinterleave, scale anc by log2e, cast bf16, norms + diag ----
// one wave per pair; 4 pairs per block
__global__ __launch_bounds__(256) void prep_kernel(
    const float* __restrict__ img,
    ushort* __restrict__ anc_bf, ushort* __restrict__ pos_bf,
    float* __restrict__ diag, float* __restrict__ na, float* __restrict__ npn) {
  int i = blockIdx.x * 4 + (threadIdx.x >> 6);
  int lane = threadIdx.x & 63;  // handles 2 elements per row
  const float2* ar = (const float2*)(img + (size_t)(2 * i) * DIM);
  const float2* pr = (const float2*)(img + (size_t)(2 * i + 1) * DIM);
  float2 a2 = ar[lane];
  float2 p2 = pr[lane];

  // anc pre-scaled by log2e so MFMA output is already in log2 units
  __hip_bfloat16 ax = __float2bfloat16(a2.x * LOG2E), ay = __float2bfloat16(a2.y * LOG2E);
  __hip_bfloat16 px = __float2bfloat16(p2.x), py = __float2bfloat16(p2.y);
  ushort2 av, pv;
  av.x = *(ushort*)&ax; av.y = *(ushort*)&ay;
  pv.x = *(ushort*)&px; pv.y = *(ushort*)&py;
  *(ushort2*)(anc_bf + (size_t)i * DIM + 2 * lane) = av;
  *(ushort2*)(pos_bf + (size_t)i * DIM + 2 * lane) = pv;

  float sa = a2.x * a2.x + a2.y * a2.y;
  float sp = p2.x * p2.x + p2.y * p2.y;
  float sd = a2.x * p2.x + a2.y * p2.y;
  #pragma unroll
  for (int off = 32; off; off >>= 1) {
    sa += __shfl_xor(sa, off);
    sp += __shfl_xor(sp, off);
    sd += __shfl_xor(sd, off);
  }
  if (lane == 0) {
    diag[i] = sd;          // ln-units (raw dot)
    na[i] = sqrtf(sa);
    npn[i] = sqrtf(sp);
  }
}

// ---------------- main: fused GEMM (bf16 MFMA) + fixed-shift sum-exp ----------------
// grid = 32 rowblocks * 32 colsplits. Block: 4 waves x 64 rows = 256 rows,
// cols [cs*256, cs*256+256). A frags in registers (64 VGPR), 16 MFMAs per B tile.
__global__ __launch_bounds__(256, 4) void lse_kernel(
    const ushort* __restrict__ anc_bf, const ushort* __restrict__ pos_bf,
    float* __restrict__ part_s) {
  int tid = threadIdx.x;
  int w = tid >> 6, lane = tid & 63;
  int rb = blockIdx.x >> 5, cs = blockIdx.x & 31;
  int row0 = rb * ROWS_PER_BLOCK + w * 64;
  int colbase = cs * COLS_PER_BLOCK;
  int lrow = lane & 15, g = lane >> 4;

  // A fragments: 64 rows x 128 K, resident in registers (16 x short8)
  short8 afrag[4][4];
  #pragma unroll
  for (int rt = 0; rt < 4; ++rt) {
    const ushort* ab = anc_bf + (size_t)(row0 + rt * 16 + lrow) * DIM + g * 8;
    #pragma unroll
    for (int ks = 0; ks < 4; ++ks)
      afrag[rt][ks] = *(const short8*)(ab + ks * 32);
  }

  float s[16];
  #pragma unroll
  for (int i = 0; i < 16; ++i) s[i] = 0.f;

  const f32x4 cinit = {-SHIFT, -SHIFT, -SHIFT, -SHIFT};
  const ushort* bbase = pos_bf + (size_t)(colbase + lrow) * DIM + g * 8;

  for (int ct = 0; ct < CT_PER_BLOCK; ++ct) {
    const ushort* bp = bbase + (size_t)ct * 16 * DIM;
    short8 b[4];
    #pragma unroll
    for (int ks = 0; ks < 4; ++ks)
      b[ks] = *(const short8*)(bp + ks * 32);
    #pragma unroll
    for (int rt = 0; rt < 4; ++rt) {
      f32x4 acc = __builtin_amdgcn_mfma_f32_16x16x32_bf16(afrag[rt][0], b[0], cinit, 0, 0, 0);
      acc = __builtin_amdgcn_mfma_f32_16x16x32_bf16(afrag[rt][1], b[1], acc, 0, 0, 0);
      acc = __builtin_amdgcn_mfma_f32_16x16x32_bf16(afrag[rt][2], b[2], acc, 0, 0, 0);
      acc = __builtin_amdgcn_mfma_f32_16x16x32_bf16(afrag[rt][3], b[3], acc, 0, 0, 0);
      // acc[r] = G[row][col]*log2e - 64 ; just sum-exp, no max tracking
      #pragma unroll
      for (int r = 0; r < 4; ++r)
        s[rt * 4 + r] += exp2f(acc[r]);
    }
  }

  // reduce s across the 16 lanes sharing each row (same g group)
  #pragma unroll
  for (int i = 0; i < 16; ++i) {
    float ss = s[i];
    ss += __shfl_xor(ss, 1);
    ss += __shfl_xor(ss, 2);
    ss += __shfl_xor(ss, 4);
    ss += __shfl_xor(ss, 8);
    s[i] = ss;
  }
  if (lrow == 0) {
    #pragma unroll
    for (int rt = 0; rt < 4; ++rt)
      #pragma unroll
      for (int r = 0; r < 4; ++r)
        part_s[(size_t)(row0 + rt * 16 + g * 4 + r) * CS + cs] = s[rt * 4 + r];
  }
}

// ---------------- merge: combine column splits, add diag/norm terms ----------------
__global__ __launch_bounds__(256) void merge_kernel(
    const float* __restrict__ part_s,
    const float* __restrict__ diag, const float* __restrict__ na,
    const float* __restrict__ npn, float* __restrict__ blocksum) {
  int i = blockIdx.x * 256 + threadIdx.x;
  const f32x4* ps = (const f32x4*)(part_s + (size_t)i * CS);
  float S = 0.f;
  #pragma unroll
  for (int c = 0; c < CS / 4; ++c) {
    f32x4 v = ps[c];
    S += v.x + v.y + v.z + v.w;
  }
  float lse = (SHIFT + log2f(S)) * LN2;
  float contrib = (lse - diag[i]) * (1.0f / N_PAIR)
                + L2REG * (na[i] * (1.0f / N_PAIR) + npn[i] * (1.0f / DIM));
  #pragma unroll
  for (int off = 32; off; off >>= 1) contrib += __shfl_xor(contrib, off);
  __shared__ float red[4];
  int lane = threadIdx.x & 63, wv = threadIdx.x >> 6;
  if (lane == 0) red[wv] = contrib;
  __syncthreads();
  if (threadIdx.x == 0)
    blocksum[blockIdx.x] = red[0] + red[1] + red[2] + red[3];
}

// ---------------- final: reduce 32 block sums ----------------
__global__ __launch_bounds__(64) void final_kernel(
    const float* __restrict__ blocksum, float* __restrict__ out, int nblocks) {
  float v = ((int)threadIdx.x < nblocks) ? blocksum[threadIdx.x] : 0.f;
  #pragma unroll
  for (int off = 32; off; off >>= 1) v += __shfl_xor(v, off);
  if (threadIdx.x == 0) out[0] = v;
}

extern "C" void kernel_launch(void* const* d_in, const int* in_sizes, int n_in,
                              void* d_out, int out_size, void* d_ws, size_t ws_size,
                              hipStream_t stream) {
  const float* img = (const float*)d_in[0];
  float* out = (float*)d_out;

  char* w = (char*)d_ws;
  ushort* anc_bf = (ushort*)w;                                  // 2 MB
  ushort* pos_bf = (ushort*)(w + (size_t)2 * 1024 * 1024);      // 2 MB
  float* diag = (float*)(w + (size_t)4 * 1024 * 1024);          // 32 KB
  float* na = diag + N_PAIR;                                    // 32 KB
  float* npn = na + N_PAIR;                                     // 32 KB
  float* part_s = npn + N_PAIR;                                 // 1 MB
  float* blocksum = part_s + (size_t)N_PAIR * CS;               // 128 B

  prep_kernel<<<N_PAIR / 4, 256, 0, stream>>>(img, anc_bf, pos_bf, diag, na, npn);
  lse_kernel<<<(N_PAIR / ROWS_PER_BLOCK) * CS, 256, 0, stream>>>(anc_bf, pos_bf, part_s);
  merge_kernel<<<N_PAIR / 256, 256, 0, stream>>>(part_s, diag, na, npn, blocksum);
  final_kernel<<<1, 64, 0, stream>>>(blocksum, out, N_PAIR / 256);
}